// Round 1
// baseline (119.197 us; speedup 1.0000x reference)
//
#include <hip/hip_runtime.h>

// Problem constants (from reference): N=4096, D=512, C=100, P=64
#define D 512
#define P 64
#define WPB 4           // waves per block -> block = 256 threads
#define NB 2            // boxes per wave (same class) -> proto traffic / NB
#define MAXC 256        // LDS histogram capacity (C=100)
#define EPS_COS 1e-8f
#define EPS_INV 1e-5f

__device__ __forceinline__ float wave_sum(float v) {
#pragma unroll
    for (int m = 32; m >= 1; m >>= 1) v += __shfl_xor(v, m, 64);
    return v;
}

// Kernel A: pp[r] = ||protos[r]||^2 for r in [0, C*P)
__global__ __launch_bounds__(256) void proto_norm_kernel(
    const float* __restrict__ protos, float* __restrict__ pp, int rows)
{
    const int lane = threadIdx.x & 63;
    const int wave = threadIdx.x >> 6;
    const int r = blockIdx.x * WPB + wave;
    if (r >= rows) return;
    const float* row = protos + (size_t)r * D;
    const float4 a = *(const float4*)(row + lane * 4);
    const float4 b = *(const float4*)(row + 256 + lane * 4);
    float s = a.x*a.x + a.y*a.y + a.z*a.z + a.w*a.w
            + b.x*b.x + b.y*b.y + b.z*b.z + b.w*b.w;
    s = wave_sum(s);
    if (lane == 0) pp[r] = s;
}

// Kernel B: counting-sort boxes by class into groups of NB same-class boxes.
// slots[g*NB + k] = box id (or -1 pad). gcount[0] = number of groups G.
__global__ __launch_bounds__(1024) void build_groups_kernel(
    const int* __restrict__ cls_ids, int* __restrict__ slots,
    int* __restrict__ gcount, int N, int C)
{
    __shared__ int cnt[MAXC], base[MAXC], fill[MAXC];
    __shared__ int sG;
    const int tid = threadIdx.x;
    for (int c = tid; c < C; c += 1024) { cnt[c] = 0; fill[c] = 0; }
    __syncthreads();
    for (int n = tid; n < N; n += 1024) atomicAdd(&cnt[cls_ids[n]], 1);
    __syncthreads();
    if (tid == 0) {
        int gb = 0;
        for (int c = 0; c < C; ++c) { base[c] = gb; gb += (cnt[c] + NB - 1) / NB; }
        sG = gb;
        gcount[0] = gb;
    }
    __syncthreads();
    const int G = sG;
    for (int i = tid; i < G * NB; i += 1024) slots[i] = -1;
    __syncthreads();
    for (int n = tid; n < N; n += 1024) {
        const int c = cls_ids[n];
        const int p = atomicAdd(&fill[c], 1);
        slots[base[c] * NB + p] = n;
    }
}

__device__ __forceinline__ void box_epilogue(
    float r_dot, float r_l1, float ff, float s_pp, int myp,
    float& prob_o, int& bidx_o)
{
    const float fnorm = fmaxf(sqrtf(ff),   EPS_COS);
    const float pnorm = fmaxf(sqrtf(s_pp), EPS_COS);
    const float d_cos = 1.0f - r_dot / (fnorm * pnorm);
    const float d_l1  = r_l1 * (1.0f / (float)D);
    const float d_l2  = (ff - 2.0f * r_dot + s_pp) * (1.0f / (float)D);

    float s[3];
    s[0] = 1.0f / (d_cos + EPS_INV);
    s[1] = 1.0f / (d_l1  + EPS_INV);
    s[2] = 1.0f / (d_l2  + EPS_INV);

    float prob = 0.f;
#pragma unroll
    for (int i = 0; i < 3; ++i) {
        float m = s[i];
#pragma unroll
        for (int w = 32; w >= 1; w >>= 1) m = fmaxf(m, __shfl_xor(m, w, 64));
        const float e = expf(s[i] - m);
        const float denom = wave_sum(e);
        prob += e / denom;
    }
    prob *= (1.0f / 3.0f);

    // argmax over protos, first-index tie-break (compare true proto indices)
    float best = prob;
    int   bidx = myp;
#pragma unroll
    for (int w = 32; w >= 1; w >>= 1) {
        const float ov = __shfl_xor(best, w, 64);
        const int   oi = __shfl_xor(bidx, w, 64);
        if (ov > best || (ov == best && oi < bidx)) { best = ov; bidx = oi; }
    }
    prob_o = prob;
    bidx_o = bidx;
}

// Kernel C: one wave per group of NB same-class boxes. Prototypes streamed
// once per wave serve NB boxes; consecutive groups are same-class so a
// block's 4 waves (and XCD-chunked neighbors) hit L1/L2 on proto rows.
__global__ __launch_bounds__(WPB * 64) void proto_probs_kernel(
    const float* __restrict__ feats,        // [N, D]
    const float* __restrict__ protos,       // [C, P, D]
    const int*   __restrict__ cls_ids,      // [N]
    const int*   __restrict__ proto_labels, // [C, P]
    const float* __restrict__ ppbuf,        // [C*P] ||p||^2
    const int*   __restrict__ slots,        // [G*NB] box ids (-1 pad)
    const int*   __restrict__ gcount,       // [1] G
    float* __restrict__ out,                // [N] labels ++ [N, P] probs
    int N)
{
    const int lane = threadIdx.x & 63;
    const int wave = threadIdx.x >> 6;

    // Bijective chunked XCD swizzle (m204): consecutive swz ids come from
    // blockIdx stride-8 apart -> each XCD's L2 gets a contiguous class run.
    const int nb  = gridDim.x;
    const int q   = nb >> 3, r = nb & 7;
    const int xcd = blockIdx.x & 7, bix = blockIdx.x >> 3;
    const int swz = (xcd < r ? xcd * (q + 1) : r * (q + 1) + (xcd - r) * q) + bix;

    const int g = swz * WPB + wave;
    if (g >= gcount[0]) return;

    const int b0 = slots[g * NB + 0];
    const int b1 = slots[g * NB + 1];
    const bool v1 = (b1 >= 0);
    const int n0 = b0;
    const int n1 = v1 ? b1 : b0;

    const int cls = cls_ids[n0];
    const float* fa = feats  + (size_t)n0 * D;
    const float* fb = feats  + (size_t)n1 * D;
    const float* pr = protos + (size_t)cls * (P * D);

    const float4 a0 = *(const float4*)(fa + lane * 4);
    const float4 a1 = *(const float4*)(fa + 256 + lane * 4);
    const float4 c0 = *(const float4*)(fb + lane * 4);
    const float4 c1 = *(const float4*)(fb + 256 + lane * 4);

    float ffa = a0.x*a0.x + a0.y*a0.y + a0.z*a0.z + a0.w*a0.w
              + a1.x*a1.x + a1.y*a1.y + a1.z*a1.z + a1.w*a1.w;
    float ffb = c0.x*c0.x + c0.y*c0.y + c0.z*c0.z + c0.w*c0.w
              + c1.x*c1.x + c1.y*c1.y + c1.z*c1.z + c1.w*c1.w;
    ffa = wave_sum(ffa);
    ffb = wave_sum(ffb);

    const int jsel = (lane >> 3) & 7;   // proto-within-group this lane ends with
    const int gown = lane & 7;          // group whose result this lane keeps
    const bool hi32 = (lane & 32) != 0;
    const bool hi16 = (lane & 16) != 0;
    const bool hi8  = (lane & 8)  != 0;

    float rdA = 0.f, rlA = 0.f, rdB = 0.f, rlB = 0.f;

    for (int gg = 0; gg < 8; ++gg) {
        float pdA[8], plA[8], pdB[8], plB[8];
#pragma unroll
        for (int j = 0; j < 8; ++j) {
            const float* row = pr + (size_t)(8 * gg + j) * D;
            const float4 q0 = *(const float4*)(row + lane * 4);
            const float4 q1 = *(const float4*)(row + 256 + lane * 4);
            float dA, lA, dB, lB, t;
            dA  = a0.x*q0.x; t = a0.x - q0.x; lA  = fabsf(t);
            dA += a0.y*q0.y; t = a0.y - q0.y; lA += fabsf(t);
            dA += a0.z*q0.z; t = a0.z - q0.z; lA += fabsf(t);
            dA += a0.w*q0.w; t = a0.w - q0.w; lA += fabsf(t);
            dA += a1.x*q1.x; t = a1.x - q1.x; lA += fabsf(t);
            dA += a1.y*q1.y; t = a1.y - q1.y; lA += fabsf(t);
            dA += a1.z*q1.z; t = a1.z - q1.z; lA += fabsf(t);
            dA += a1.w*q1.w; t = a1.w - q1.w; lA += fabsf(t);
            dB  = c0.x*q0.x; t = c0.x - q0.x; lB  = fabsf(t);
            dB += c0.y*q0.y; t = c0.y - q0.y; lB += fabsf(t);
            dB += c0.z*q0.z; t = c0.z - q0.z; lB += fabsf(t);
            dB += c0.w*q0.w; t = c0.w - q0.w; lB += fabsf(t);
            dB += c1.x*q1.x; t = c1.x - q1.x; lB += fabsf(t);
            dB += c1.y*q1.y; t = c1.y - q1.y; lB += fabsf(t);
            dB += c1.z*q1.z; t = c1.z - q1.z; lB += fabsf(t);
            dB += c1.w*q1.w; t = c1.w - q1.w; lB += fabsf(t);
            pdA[j] = dA; plA[j] = lA; pdB[j] = dB; plB[j] = lB;
        }
        // Halving step 1: distance 32, 8 -> 4 partials
#pragma unroll
        for (int k = 0; k < 4; ++k) {
            const float sdA = hi32 ? pdA[k] : pdA[k + 4];
            const float slA = hi32 ? plA[k] : plA[k + 4];
            const float sdB = hi32 ? pdB[k] : pdB[k + 4];
            const float slB = hi32 ? plB[k] : plB[k + 4];
            const float rd0 = __shfl_xor(sdA, 32, 64);
            const float rl0 = __shfl_xor(slA, 32, 64);
            const float rd1 = __shfl_xor(sdB, 32, 64);
            const float rl1 = __shfl_xor(slB, 32, 64);
            pdA[k] = (hi32 ? pdA[k + 4] : pdA[k]) + rd0;
            plA[k] = (hi32 ? plA[k + 4] : plA[k]) + rl0;
            pdB[k] = (hi32 ? pdB[k + 4] : pdB[k]) + rd1;
            plB[k] = (hi32 ? plB[k + 4] : plB[k]) + rl1;
        }
        // Halving step 2: distance 16, 4 -> 2
#pragma unroll
        for (int k = 0; k < 2; ++k) {
            const float sdA = hi16 ? pdA[k] : pdA[k + 2];
            const float slA = hi16 ? plA[k] : plA[k + 2];
            const float sdB = hi16 ? pdB[k] : pdB[k + 2];
            const float slB = hi16 ? plB[k] : plB[k + 2];
            const float rd0 = __shfl_xor(sdA, 16, 64);
            const float rl0 = __shfl_xor(slA, 16, 64);
            const float rd1 = __shfl_xor(sdB, 16, 64);
            const float rl1 = __shfl_xor(slB, 16, 64);
            pdA[k] = (hi16 ? pdA[k + 2] : pdA[k]) + rd0;
            plA[k] = (hi16 ? plA[k + 2] : plA[k]) + rl0;
            pdB[k] = (hi16 ? pdB[k + 2] : pdB[k]) + rd1;
            plB[k] = (hi16 ? plB[k + 2] : plB[k]) + rl1;
        }
        // Halving step 3: distance 8, 2 -> 1
        {
            const float sdA = hi8 ? pdA[0] : pdA[1];
            const float slA = hi8 ? plA[0] : plA[1];
            const float sdB = hi8 ? pdB[0] : pdB[1];
            const float slB = hi8 ? plB[0] : plB[1];
            const float rd0 = __shfl_xor(sdA, 8, 64);
            const float rl0 = __shfl_xor(slA, 8, 64);
            const float rd1 = __shfl_xor(sdB, 8, 64);
            const float rl1 = __shfl_xor(slB, 8, 64);
            pdA[0] = (hi8 ? pdA[1] : pdA[0]) + rd0;
            plA[0] = (hi8 ? plA[1] : plA[0]) + rl0;
            pdB[0] = (hi8 ? pdB[1] : pdB[0]) + rd1;
            plB[0] = (hi8 ? plB[1] : plB[0]) + rl1;
        }
        // Finish: butterfly over distances 4,2,1
#pragma unroll
        for (int m = 4; m >= 1; m >>= 1) {
            pdA[0] += __shfl_xor(pdA[0], m, 64);
            plA[0] += __shfl_xor(plA[0], m, 64);
            pdB[0] += __shfl_xor(pdB[0], m, 64);
            plB[0] += __shfl_xor(plB[0], m, 64);
        }
        if (gown == gg) { rdA = pdA[0]; rlA = plA[0]; rdB = pdB[0]; rlB = plB[0]; }
    }

    const int myp = 8 * gown + jsel;    // proto index this lane owns
    const float s_pp = ppbuf[cls * P + myp];   // same class/proto for both boxes

    float probA; int bidxA;
    box_epilogue(rdA, rlA, ffa, s_pp, myp, probA, bidxA);
    out[(size_t)N + (size_t)n0 * P + myp] = probA;
    if (lane == 0) out[n0] = (float)proto_labels[cls * P + bidxA];

    if (v1) {
        float probB; int bidxB;
        box_epilogue(rdB, rlB, ffb, s_pp, myp, probB, bidxB);
        out[(size_t)N + (size_t)n1 * P + myp] = probB;
        if (lane == 0) out[n1] = (float)proto_labels[cls * P + bidxB];
    }
}

extern "C" void kernel_launch(void* const* d_in, const int* in_sizes, int n_in,
                              void* d_out, int out_size, void* d_ws, size_t ws_size,
                              hipStream_t stream) {
    const float* feats        = (const float*)d_in[0];
    const float* protos       = (const float*)d_in[1];
    const int*   cls_ids      = (const int*)d_in[2];
    const int*   proto_labels = (const int*)d_in[3];
    float* out = (float*)d_out;

    const int N    = in_sizes[2];           // 4096
    const int rows = in_sizes[1] / D;       // C*P = 6400
    const int C    = rows / P;              // 100

    // Workspace layout: pp[C*P] floats | gcount[1] int | slots[Gmax*NB] int
    float* pp     = (float*)d_ws;
    int*   gcount = (int*)((char*)d_ws + (size_t)rows * sizeof(float));
    int*   slots  = gcount + 1;

    const int Gmax    = (N + C * (NB - 1)) / NB;    // upper bound on groups
    const int mblocks = (Gmax + WPB - 1) / WPB;

    proto_norm_kernel<<<(rows + WPB - 1) / WPB, WPB * 64, 0, stream>>>(
        protos, pp, rows);
    build_groups_kernel<<<1, 1024, 0, stream>>>(cls_ids, slots, gcount, N, C);
    proto_probs_kernel<<<mblocks, WPB * 64, 0, stream>>>(
        feats, protos, cls_ids, proto_labels, pp, slots, gcount, out, N);
}